// Round 1
// baseline (154.398 us; speedup 1.0000x reference)
//
#include <hip/hip_runtime.h>

#define CH 64      // channels
#define NN 4096    // h*w
#define NB 4       // batch

typedef unsigned short u16;
typedef __attribute__((ext_vector_type(8))) short bf16x8;
typedef __attribute__((ext_vector_type(4))) float f32x4;

// f32 -> bf16 (RNE), scalar
static __device__ __forceinline__ u16 bf16r(float f) {
  union { float f; unsigned u; } v; v.f = f;
  unsigned x = v.u;
  x += 0x7fffu + ((x >> 16) & 1u);
  return (u16)(x >> 16);
}
// pack two f32 -> u32 of two bf16 (lo = a, hi = b)
static __device__ __forceinline__ unsigned pk2(float a, float b) {
  union { float f; unsigned u; } va, vb; va.f = a; vb.f = b;
  unsigned x = va.u, y = vb.u;
  x += 0x7fffu + ((x >> 16) & 1u);
  y += 0x7fffu + ((y >> 16) & 1u);
  return (x >> 16) | (y & 0xffff0000u);
}

// ---------------- Kernel A: QKV projection ----------------
// x: [b][c][n] f32.  Writes Q,K: [b][n][8] bf16 ; V: [b][ch][n] bf16.
// 256 blocks x 256 thr. Wave g: 16 v-channels [16g,16g+16); wave 0 also q[0..7],
// wave 1 also k[0..7]. Weights via wave-uniform scalar loads.
__global__ __launch_bounds__(256) void qkv_proj(
    const float* __restrict__ x,
    const float* __restrict__ wq, const float* __restrict__ bq,
    const float* __restrict__ wk, const float* __restrict__ bk,
    const float* __restrict__ wv, const float* __restrict__ bv,
    u16* __restrict__ Qb, u16* __restrict__ Kb, u16* __restrict__ Vb) {
  const int blk = blockIdx.x;
  const int b = blk >> 6;                  // 64 tiles of 64 positions per batch
  const int n0 = (blk & 63) << 6;
  const int t = threadIdx.x;
  const int p = t & 63;
  const int g = __builtin_amdgcn_readfirstlane(t >> 6);  // wave id, SGPR
  const float* xb = x + (size_t)b * CH * NN + n0 + p;

  float vacc[16];
#pragma unroll
  for (int j = 0; j < 16; ++j) vacc[j] = 0.f;
  float aacc[8];
#pragma unroll
  for (int d = 0; d < 8; ++d) aacc[d] = 0.f;

  const int vch0 = g << 4;
  const float* wA = (g == 0) ? wq : wk;

#pragma unroll 4
  for (int c = 0; c < CH; ++c) {
    float xv = xb[(size_t)c * NN];         // coalesced (64 consecutive p)
#pragma unroll
    for (int j = 0; j < 16; ++j)
      vacc[j] = fmaf(wv[(vch0 + j) * CH + c], xv, vacc[j]);  // s_load (uniform)
    if (g < 2) {
#pragma unroll
      for (int d = 0; d < 8; ++d)
        aacc[d] = fmaf(wA[d * CH + c], xv, aacc[d]);
    }
  }

  const size_t vbase = ((size_t)b * CH + vch0) * NN + n0 + p;
#pragma unroll
  for (int j = 0; j < 16; ++j)
    Vb[vbase + (size_t)j * NN] = bf16r(vacc[j] + bv[vch0 + j]);

  if (g < 2) {
    const float* bias = (g == 0) ? bq : bk;
    float o0 = aacc[0] + bias[0], o1 = aacc[1] + bias[1];
    float o2 = aacc[2] + bias[2], o3 = aacc[3] + bias[3];
    float o4 = aacc[4] + bias[4], o5 = aacc[5] + bias[5];
    float o6 = aacc[6] + bias[6], o7 = aacc[7] + bias[7];
    uint4 pkv;
    pkv.x = pk2(o0, o1); pkv.y = pk2(o2, o3);
    pkv.z = pk2(o4, o5); pkv.w = pk2(o6, o7);
    u16* dst = ((g == 0) ? Qb : Kb) + ((size_t)b * NN + n0 + p) * 8;
    *reinterpret_cast<uint4*>(dst) = pkv;   // 16B coalesced
  }
}

// ---------------- Kernel B: fused flash attention + epilogue ----------------
// grid (NN/64, NB), 256 thr = 4 independent waves, 16 q-rows per wave.
// S^T = K·Q^T via mfma(16x16x32 bf16, d=8 zero-padded); online softmax per
// column q; P^T through LDS; O^T = V^T·P^T; out = gamma*O/l + x.
__global__ __launch_bounds__(256) void flash_attn(
    const float* __restrict__ x, const float* __restrict__ gamma,
    const u16* __restrict__ Qb, const u16* __restrict__ Kb,
    const u16* __restrict__ Vb, float* __restrict__ out) {
  __shared__ unsigned p_lds32[4][16][16];   // per-wave [16 q][32 keys] bf16
  const int b = blockIdx.y;
  const int w = __builtin_amdgcn_readfirstlane(threadIdx.x >> 6);
  const int lane = threadIdx.x & 63;
  const int q = lane & 15;                  // col (q-row) / A-frag row index
  const int g = lane >> 4;                  // k-slot group
  const int q0 = (blockIdx.x << 6) + (w << 4);

  // Q fragment (B operand): lanes g==0 hold q[0..7], others zero (d pad)
  bf16x8 qf = {0,0,0,0,0,0,0,0};
  if (g == 0)
    qf = *reinterpret_cast<const bf16x8*>(Qb + ((size_t)b * NN + q0 + q) * 8);

  f32x4 acc0 = {0,0,0,0}, acc1 = {0,0,0,0}, acc2 = {0,0,0,0}, acc3 = {0,0,0,0};
  float m = -INFINITY, l = 0.f;

  const u16* Kbase = Kb + (size_t)b * NN * 8;
  const u16* Vbase = Vb + (size_t)b * CH * NN;

  // prologue prefetch (tile k0 = 0)
  bf16x8 kf0 = {0,0,0,0,0,0,0,0}, kf1 = {0,0,0,0,0,0,0,0};
  if (g == 0) {
    kf0 = *reinterpret_cast<const bf16x8*>(Kbase + (size_t)q * 8);
    kf1 = *reinterpret_cast<const bf16x8*>(Kbase + (size_t)(16 + q) * 8);
  }
  bf16x8 vf0, vf1, vf2, vf3;
  {
    const u16* vp = Vbase + (size_t)q * NN + g * 8;
    vf0 = *reinterpret_cast<const bf16x8*>(vp);
    vf1 = *reinterpret_cast<const bf16x8*>(vp + (size_t)16 * NN);
    vf2 = *reinterpret_cast<const bf16x8*>(vp + (size_t)32 * NN);
    vf3 = *reinterpret_cast<const bf16x8*>(vp + (size_t)48 * NN);
  }

  for (int k0 = 0; k0 < NN; k0 += 32) {
    // ---- prefetch next 32-key tile (clamped to stay in-bounds) ----
    const int kn = (k0 + 32 < NN) ? (k0 + 32) : 0;
    bf16x8 kf0n = {0,0,0,0,0,0,0,0}, kf1n = {0,0,0,0,0,0,0,0};
    if (g == 0) {
      kf0n = *reinterpret_cast<const bf16x8*>(Kbase + (size_t)(kn + q) * 8);
      kf1n = *reinterpret_cast<const bf16x8*>(Kbase + (size_t)(kn + 16 + q) * 8);
    }
    bf16x8 vf0n, vf1n, vf2n, vf3n;
    {
      const u16* vp = Vbase + (size_t)q * NN + kn + g * 8;
      vf0n = *reinterpret_cast<const bf16x8*>(vp);
      vf1n = *reinterpret_cast<const bf16x8*>(vp + (size_t)16 * NN);
      vf2n = *reinterpret_cast<const bf16x8*>(vp + (size_t)32 * NN);
      vf3n = *reinterpret_cast<const bf16x8*>(vp + (size_t)48 * NN);
    }

    // ---- S^T = K · Q^T : rows = keys (4g+r), cols = q ----
    f32x4 zz = {0,0,0,0};
    f32x4 s0 = __builtin_amdgcn_mfma_f32_16x16x32_bf16(kf0, qf, zz, 0, 0, 0);
    f32x4 s1 = __builtin_amdgcn_mfma_f32_16x16x32_bf16(kf1, qf, zz, 0, 0, 0);

    // ---- online softmax over keys (per column q) ----
    float tmax = fmaxf(fmaxf(fmaxf(s0[0], s0[1]), fmaxf(s0[2], s0[3])),
                       fmaxf(fmaxf(s1[0], s1[1]), fmaxf(s1[2], s1[3])));
    tmax = fmaxf(tmax, __shfl_xor(tmax, 16));
    tmax = fmaxf(tmax, __shfl_xor(tmax, 32));

    if (__any(tmax > m)) {                 // rescale only when a max increases
      float mn = fmaxf(m, tmax);
      float sc = __expf(m - mn);           // exp(-inf)=0 on first tile
      l *= sc;
      acc0 *= sc; acc1 *= sc; acc2 *= sc; acc3 *= sc;
      m = mn;
    }

    float p00 = __expf(s0[0] - m), p01 = __expf(s0[1] - m);
    float p02 = __expf(s0[2] - m), p03 = __expf(s0[3] - m);
    float p10 = __expf(s1[0] - m), p11 = __expf(s1[1] - m);
    float p12 = __expf(s1[2] - m), p13 = __expf(s1[3] - m);
    float ps = ((p00 + p01) + (p02 + p03)) + ((p10 + p11) + (p12 + p13));
    ps += __shfl_xor(ps, 16);
    ps += __shfl_xor(ps, 32);
    l += ps;

    // ---- P^T -> LDS [q][key_local] (keys 4g+r / 16+4g+r), packed bf16 ----
    p_lds32[w][q][2 * g]     = pk2(p00, p01);
    p_lds32[w][q][2 * g + 1] = pk2(p02, p03);
    p_lds32[w][q][8 + 2 * g]     = pk2(p10, p11);
    p_lds32[w][q][8 + 2 * g + 1] = pk2(p12, p13);

    // B fragment for PV: 8 consecutive keys per lane at [q][8g..8g+7]
    bf16x8 pb = *reinterpret_cast<bf16x8*>(&p_lds32[w][q][4 * g]);

    // ---- O^T += V^T · P^T (4 channel groups of 16) ----
    acc0 = __builtin_amdgcn_mfma_f32_16x16x32_bf16(vf0, pb, acc0, 0, 0, 0);
    acc1 = __builtin_amdgcn_mfma_f32_16x16x32_bf16(vf1, pb, acc1, 0, 0, 0);
    acc2 = __builtin_amdgcn_mfma_f32_16x16x32_bf16(vf2, pb, acc2, 0, 0, 0);
    acc3 = __builtin_amdgcn_mfma_f32_16x16x32_bf16(vf3, pb, acc3, 0, 0, 0);

    kf0 = kf0n; kf1 = kf1n;
    vf0 = vf0n; vf1 = vf1n; vf2 = vf2n; vf3 = vf3n;
  }

  // ---- epilogue: out[b][ch][q0+q] = gamma * acc/l + x ----
  const float gm = gamma[0] / l;           // per-lane l (col q), replicated over g
  const size_t obase = (size_t)b * CH * NN + q0 + q;
#pragma unroll
  for (int r = 0; r < 4; ++r) {
    size_t i0 = obase + (size_t)(4 * g + r) * NN;
    out[i0] = fmaf(gm, acc0[r], x[i0]);
    size_t i1 = obase + (size_t)(16 + 4 * g + r) * NN;
    out[i1] = fmaf(gm, acc1[r], x[i1]);
    size_t i2 = obase + (size_t)(32 + 4 * g + r) * NN;
    out[i2] = fmaf(gm, acc2[r], x[i2]);
    size_t i3 = obase + (size_t)(48 + 4 * g + r) * NN;
    out[i3] = fmaf(gm, acc3[r], x[i3]);
  }
}

extern "C" void kernel_launch(void* const* d_in, const int* in_sizes, int n_in,
                              void* d_out, int out_size, void* d_ws, size_t ws_size,
                              hipStream_t stream) {
  const float* x     = (const float*)d_in[0];
  const float* wq    = (const float*)d_in[1];
  const float* bq    = (const float*)d_in[2];
  const float* wk    = (const float*)d_in[3];
  const float* bk    = (const float*)d_in[4];
  const float* wv    = (const float*)d_in[5];
  const float* bv    = (const float*)d_in[6];
  const float* gamma = (const float*)d_in[7];
  float* out = (float*)d_out;

  // workspace layout (bf16): Q [4][4096][8] (256KB) | K [4][4096][8] (256KB)
  //                          | V [4][64][4096] (2MB)   total 2.5 MB
  u16* Qb = (u16*)d_ws;
  u16* Kb = Qb + (size_t)NB * NN * 8;
  u16* Vb = Kb + (size_t)NB * NN * 8;

  qkv_proj<<<dim3(NB * (NN / 64)), dim3(256), 0, stream>>>(
      x, wq, bq, wk, bk, wv, bv, Qb, Kb, Vb);
  flash_attn<<<dim3(NN / 64, NB), dim3(256), 0, stream>>>(
      x, gamma, Qb, Kb, Vb, out);
}